// Round 5
// baseline (1149.215 us; speedup 1.0000x reference)
//
#include <hip/hip_runtime.h>

#define DT_F 0.01f
#define EPS_F 1e-5f

typedef _Float16 f16;
typedef _Float16 f16x8 __attribute__((ext_vector_type(8)));
typedef float f32x4 __attribute__((ext_vector_type(4)));

__device__ __forceinline__ float sigm(float x) { return 1.0f / (1.0f + __expf(-x)); }
__device__ __forceinline__ float tanhf_fast(float x) {
  float e = __expf(-2.0f * fabsf(x));
  float t = (1.0f - e) / (1.0f + e);
  return x < 0.0f ? -t : t;
}

// evtab[k*B + sid] = (last obs index in event k's window with sample_ids==sid) + 1, or 0.
__global__ void build_evtab_kernel(const int* __restrict__ sample_ids,
                                   const int* __restrict__ time_ptr,
                                   int* __restrict__ evtab, int B, int ope) {
  int k = blockIdx.x;
  int base = time_ptr[k];
  for (int t = threadIdx.x; t < ope; t += blockDim.x) {
    int obs = base + t;
    int sid = sample_ids[obs];
    atomicMax(&evtab[k * B + sid], obs + 1);   // last occurrence wins
  }
}

// Pack weights into per-lane MFMA B-fragment images (16x16x32 f16):
// B[k][n']: lane l holds n' = 16*tile + (l&15), k = 8*(l>>4) + j (+32*kf).
// frag f layout:
//   f in [0,24):  ODE   (g,t,kf): f = 8g + 2t + kf, W = {ghr,ghz,ghh}[n][k]
//   f in [24,48): BayesH (g,t,kf): W = gb_Whh[(64g+n)][k]
//   f in [48,60): BayesX (g,t):    f = 48 + 4g + t, W = gb_Wih[(64g+n)][kx], kx<IN else 0
__global__ void pack_frags_kernel(const float* __restrict__ ghr,
                                  const float* __restrict__ ghz,
                                  const float* __restrict__ ghh,
                                  const float* __restrict__ gbWhh,
                                  const float* __restrict__ gbWih,
                                  f16* __restrict__ frags, int IN) {
  int f = blockIdx.x;       // 0..59
  int l = threadIdx.x;      // 0..63
  for (int j = 0; j < 8; ++j) {
    float v = 0.0f;
    if (f < 48) {
      int fb = (f < 24) ? f : f - 24;
      int g = fb >> 3, t = (fb >> 1) & 3, kf = fb & 1;
      int n = 16 * t + (l & 15);
      int k = 8 * (l >> 4) + j + 32 * kf;
      if (f < 24) {
        const float* src = (g == 0) ? ghr : ((g == 1) ? ghz : ghh);
        v = src[n * 64 + k];
      } else {
        v = gbWhh[(g * 64 + n) * 64 + k];
      }
    } else {
      int fb = f - 48;
      int g = fb >> 2, t = fb & 3;
      int n = 16 * t + (l & 15);
      int kx = 8 * (l >> 4) + j;
      v = (kx < IN) ? gbWih[(g * 64 + n) * IN + kx] : 0.0f;
    }
    frags[(long)f * 512 + l * 8 + j] = (f16)v;
  }
}

// 16 samples per block, 4 waves. h in MFMA C-layout fp32 registers
// (sample row m = 4*(lane>>4)+i, gate/hidden col n = 16*wid + (lane&15)).
// Matvecs via mfma_f32_16x16x32_f16; A-images (h / r*h / x) in LDS as exact
// per-lane fragment images -> contiguous conflict-free ds_read_b128.
__global__ __launch_bounds__(256, 1) void evolve_kernel(
    const float* __restrict__ time_uniq,
    const float* __restrict__ X,
    const float* __restrict__ covs,
    const float* __restrict__ cov_W1, const float* __restrict__ cov_b1,
    const float* __restrict__ cov_W2, const float* __restrict__ cov_b2,
    const float* __restrict__ gb_bih, const float* __restrict__ gb_bhh,
    const float* __restrict__ gx_b,
    const f16* __restrict__ gfrags,
    const int* __restrict__ evtab,
    float* __restrict__ hpath,
    int B, int NE, int n_steps, int IN, int COV)
{
  __shared__ __align__(16) f16 sFragB[36 * 512];  // Bayes B-frags (36KB)
  __shared__ __align__(16) f16 sHimg[2 * 512];    // h A-image, K0/K1 (2KB)
  __shared__ __align__(16) f16 sRHimg[2 * 512];   // r*h A-image (2KB)
  __shared__ __align__(16) f16 sXimg[512];        // x A-image, K=32 (1KB)
  __shared__ float sRelu[16][65];
  __shared__ int sStep[1024];
  __shared__ int sMask[17];                       // [16] fire flags + [16]=any

  const int tid = threadIdx.x;
  const int wid = tid >> 6, lane = tid & 63;
  const int b0 = blockIdx.x * 16;
  const int n = 16 * wid + (lane & 15);   // gate/hidden column owned
  const int mrow = 4 * (lane >> 4);       // base sample row (+i)

  // stage Bayes fragments into LDS
  for (int i = tid; i < 36 * 64; i += 256)
    ((f16x8*)sFragB)[i] = ((const f16x8*)(gfrags + 24 * 512))[i];
  // zero X image once (pad lanes stay 0 forever)
  for (int i = tid; i < 512; i += 256) sXimg[i] = (f16)0.0f;
  // event firing schedule (exact fp32 semantics, proven R1)
  for (int e = tid; e < 1024; e += 256) {
    if (e < NE) {
      float tu = time_uniq[e];
      int k0 = (int)floorf((tu - EPS_F) * 100.0f) - 2;
      if (k0 < 0) k0 = 0;
      while ((float)k0 * DT_F + EPS_F < tu) ++k0;
      sStep[e] = k0;
    }
  }
  // covariates: relu hidden layer (CH=64 assumed)
  for (int idx = tid; idx < 16 * 64; idx += 256) {
    int sm = idx >> 6, u = idx & 63;
    float a = cov_b1[u];
    if (b0 + sm < B)
      for (int c = 0; c < COV; ++c)
        a = fmaf(covs[(b0 + sm) * COV + c], cov_W1[u * COV + c], a);
    sRelu[sm][u] = fmaxf(a, 0.0f);
  }
  __syncthreads();
  if (tid == 0) {  // enforce <=1 event per step, in order
    int prev = -1;
    int ne = NE < 1024 ? NE : 1024;
    for (int e = 0; e < ne; ++e) {
      int s = sStep[e];
      if (s < prev + 1) s = prev + 1;
      sStep[e] = s;
      prev = s;
    }
  }
  __syncthreads();

  // h0 = tanh(relu @ W2^T + b2) for my 4 (m,n) cells
  float h[4];
#pragma unroll
  for (int i = 0; i < 4; ++i) {
    float a = cov_b2[n];
    for (int j = 0; j < 64; ++j)
      a = fmaf(sRelu[mrow + i][j], cov_W2[n * 64 + j], a);
    h[i] = tanhf_fast(a);
  }

  // ODE B-fragments into registers (24 VGPR total)
  const f16x8* gf = (const f16x8*)gfrags;
  const f16x8 WBr0 = gf[(2 * wid + 0) * 64 + lane];
  const f16x8 WBr1 = gf[(2 * wid + 1) * 64 + lane];
  const f16x8 WBz0 = gf[(8 + 2 * wid + 0) * 64 + lane];
  const f16x8 WBz1 = gf[(8 + 2 * wid + 1) * 64 + lane];
  const f16x8 WBu0 = gf[(16 + 2 * wid + 0) * 64 + lane];
  const f16x8 WBu1 = gf[(16 + 2 * wid + 1) * 64 + lane];

  const float xr = gx_b[n], xz = gx_b[64 + n], xh = gx_b[128 + n];
  const float cbr = gb_bih[n] + gb_bhh[n];
  const float cbz = gb_bih[64 + n] + gb_bhh[64 + n];
  const float bin_ = gb_bih[128 + n], bhn_ = gb_bhh[128 + n];

  // A-image writer: value at (sample m, k-col kk)
  auto img_put = [&](f16* img, int m, int kk, float v) {
    img[(kk >> 5) * 512 + (m + ((kk & 31) >> 3) * 16) * 8 + (kk & 7)] = (f16)v;
  };

  // initial h image
#pragma unroll
  for (int i = 0; i < 4; ++i) img_put(sHimg, mrow + i, n, h[i]);

  // ---- event prefetch machinery (wave 0 only, 2 slots) ----
  int ev0 = 0, ev1 = 0;
  float2 xp0 = make_float2(0.f, 0.f), xp1 = make_float2(0.f, 0.f);
  auto issue_pf = [&](int e, int& evR, float2& xpR) {
    evR = 0; xpR.x = 0.f; xpR.y = 0.f;
    if (wid == 0 && e < NE) {
      int evv = 0;
      if (lane < 16 && b0 + lane < B) evv = evtab[(long)e * B + b0 + lane];
      evR = evv;
      int vs = __shfl(evv, lane >> 2);
      int c0 = 2 * (lane & 3);
      if (vs > 0 && c0 < IN)     xpR.x = X[(long)(vs - 1) * IN + c0];
      if (vs > 0 && c0 + 1 < IN) xpR.y = X[(long)(vs - 1) * IN + c0 + 1];
    }
  };
  auto stage_x = [&](int evv, float2 x2) {
    if (wid == 0) {
      int m = lane >> 2, c0 = 2 * (lane & 3);
      sXimg[m * 8 + c0]     = (f16)x2.x;
      sXimg[m * 8 + c0 + 1] = (f16)x2.y;
      if (lane < 16) sMask[lane] = (evv > 0) ? 1 : 0;
      unsigned long long bal = __ballot((lane < 16) && (evv > 0));
      if (lane == 0) sMask[16] = (bal != 0ULL) ? 1 : 0;
    }
  };

  int e_next = 0;
  int s_next = (NE > 0) ? sStep[0] : 0x7fffffff;
  issue_pf(0, ev0, xp0);
  issue_pf(1, ev1, xp1);
  if (NE > 0 && s_next == 0) {       // event 0 fires at step 0: stage now
    stage_x(ev0, xp0);
    issue_pf(2, ev0, xp0);
  }

#pragma unroll 1
  for (int k = 0; k < n_steps; ++k) {
    __syncthreads();                                   // B0
    f16x8 aH0 = *(const f16x8*)&sHimg[lane * 8];
    f16x8 aH1 = *(const f16x8*)&sHimg[512 + lane * 8];

    if (k == s_next) {                                 // event step (block-uniform)
      if (sMask[16]) {
        f16x8 aX = *(const f16x8*)&sXimg[lane * 8];
        const f16x8* fb = (const f16x8*)sFragB;
        f32x4 ra = {0.f, 0.f, 0.f, 0.f}, za = ra, hna = ra, ina = ra;
        ra = __builtin_amdgcn_mfma_f32_16x16x32_f16(aH0, fb[(2 * wid + 0) * 64 + lane], ra, 0, 0, 0);
        ra = __builtin_amdgcn_mfma_f32_16x16x32_f16(aH1, fb[(2 * wid + 1) * 64 + lane], ra, 0, 0, 0);
        ra = __builtin_amdgcn_mfma_f32_16x16x32_f16(aX,  fb[(24 + wid) * 64 + lane],    ra, 0, 0, 0);
        za = __builtin_amdgcn_mfma_f32_16x16x32_f16(aH0, fb[(8 + 2 * wid + 0) * 64 + lane], za, 0, 0, 0);
        za = __builtin_amdgcn_mfma_f32_16x16x32_f16(aH1, fb[(8 + 2 * wid + 1) * 64 + lane], za, 0, 0, 0);
        za = __builtin_amdgcn_mfma_f32_16x16x32_f16(aX,  fb[(24 + 4 + wid) * 64 + lane],    za, 0, 0, 0);
        hna = __builtin_amdgcn_mfma_f32_16x16x32_f16(aH0, fb[(16 + 2 * wid + 0) * 64 + lane], hna, 0, 0, 0);
        hna = __builtin_amdgcn_mfma_f32_16x16x32_f16(aH1, fb[(16 + 2 * wid + 1) * 64 + lane], hna, 0, 0, 0);
        ina = __builtin_amdgcn_mfma_f32_16x16x32_f16(aX,  fb[(24 + 8 + wid) * 64 + lane],     ina, 0, 0, 0);
#pragma unroll
        for (int i = 0; i < 4; ++i) {
          float rb = sigm(ra[i] + cbr);
          float zb = sigm(za[i] + cbz);
          float nb = tanhf_fast((ina[i] + bin_) + rb * (hna[i] + bhn_));
          float hnew = (1.0f - zb) * nb + zb * h[i];
          if (sMask[mrow + i]) h[i] = hnew;
        }
#pragma unroll
        for (int i = 0; i < 4; ++i) img_put(sHimg, mrow + i, n, h[i]);
        __syncthreads();                               // B0b
        aH0 = *(const f16x8*)&sHimg[lane * 8];
        aH1 = *(const f16x8*)&sHimg[512 + lane * 8];
      }
      ++e_next;
      s_next = (e_next < NE && e_next < 1024) ? sStep[e_next] : 0x7fffffff;
    }

    // h_rec (post-event, pre-ODE)
    {
      long base = ((long)k * B + b0) * 64;
#pragma unroll
      for (int i = 0; i < 4; ++i)
        if (b0 + mrow + i < B) hpath[base + (long)(mrow + i) * 64 + n] = h[i];
    }

    // ODE phase 1: r,z
    f32x4 racc = {0.f, 0.f, 0.f, 0.f}, zacc = racc;
    racc = __builtin_amdgcn_mfma_f32_16x16x32_f16(aH0, WBr0, racc, 0, 0, 0);
    racc = __builtin_amdgcn_mfma_f32_16x16x32_f16(aH1, WBr1, racc, 0, 0, 0);
    zacc = __builtin_amdgcn_mfma_f32_16x16x32_f16(aH0, WBz0, zacc, 0, 0, 0);
    zacc = __builtin_amdgcn_mfma_f32_16x16x32_f16(aH1, WBz1, zacc, 0, 0, 0);
    float zg[4];
#pragma unroll
    for (int i = 0; i < 4; ++i) {
      float r = sigm(racc[i] + xr);
      zg[i] = sigm(zacc[i] + xz);
      img_put(sRHimg, mrow + i, n, r * h[i]);
    }
    __syncthreads();                                   // B1
    f16x8 aR0 = *(const f16x8*)&sRHimg[lane * 8];
    f16x8 aR1 = *(const f16x8*)&sRHimg[512 + lane * 8];
    f32x4 uacc = {0.f, 0.f, 0.f, 0.f};
    uacc = __builtin_amdgcn_mfma_f32_16x16x32_f16(aR0, WBu0, uacc, 0, 0, 0);
    uacc = __builtin_amdgcn_mfma_f32_16x16x32_f16(aR1, WBu1, uacc, 0, 0, 0);
#pragma unroll
    for (int i = 0; i < 4; ++i) {
      float u = tanhf_fast(uacc[i] + xh);
      h[i] = fmaf(DT_F * (1.0f - zg[i]), u - h[i], h[i]);
      img_put(sHimg, mrow + i, n, h[i]);
    }

    // stage next event's x/mask (written post-B1, read post-next-B0)
    if (k + 1 == s_next) {
      if (e_next & 1) { stage_x(ev1, xp1); issue_pf(e_next + 2, ev1, xp1); }
      else            { stage_x(ev0, xp0); issue_pf(e_next + 2, ev0, xp0); }
    }
  }

  // h_last
  {
    long base = ((long)n_steps * B + b0) * 64;
#pragma unroll
    for (int i = 0; i < 4; ++i)
      if (b0 + mrow + i < B) hpath[base + (long)(mrow + i) * 64 + n] = h[i];
  }
}

// out[row] = relu(h[row] @ W1^T + b1) @ W2^T + b2, rows = (n_steps+1)*B
__global__ __launch_bounds__(256, 2) void head_kernel(
    const float* __restrict__ hpath, const float* __restrict__ W1,
    const float* __restrict__ b1, const float* __restrict__ W2,
    const float* __restrict__ b2, float* __restrict__ out, long nrows)
{
  __shared__ __align__(16) float sW1[64 * 128];
  __shared__ __align__(16) float sH[64 * 128];
  int tid = threadIdx.x;
  for (int idx = tid; idx < 128 * 64; idx += 256) {
    int oc = idx >> 6, j = idx & 63;
    sW1[j * 128 + oc] = W1[idx];
  }
  long row0 = (long)blockIdx.x * 128;
  for (int idx = tid; idx < 128 * 64; idx += 256) {
    int r = idx >> 6, j = idx & 63;
    long row = row0 + r;
    sH[j * 128 + r] = (row < nrows) ? hpath[row * 64 + j] : 0.0f;
  }
  __syncthreads();

  int tr = tid >> 4, tc = tid & 15;
  int r0 = tr * 8, oc0 = tc * 8;
  float acc[8][8];
#pragma unroll
  for (int s = 0; s < 8; ++s)
#pragma unroll
    for (int u = 0; u < 8; ++u) acc[s][u] = 0.0f;

#pragma unroll 4
  for (int j = 0; j < 64; ++j) {
    float4 ha = *(const float4*)&sH[j * 128 + r0];
    float4 hb = *(const float4*)&sH[j * 128 + r0 + 4];
    float4 wa = *(const float4*)&sW1[j * 128 + oc0];
    float4 wb = *(const float4*)&sW1[j * 128 + oc0 + 4];
    float hv[8] = {ha.x, ha.y, ha.z, ha.w, hb.x, hb.y, hb.z, hb.w};
    float wv[8] = {wa.x, wa.y, wa.z, wa.w, wb.x, wb.y, wb.z, wb.w};
#pragma unroll
    for (int s = 0; s < 8; ++s)
#pragma unroll
      for (int u = 0; u < 8; ++u)
        acc[s][u] = fmaf(hv[s], wv[u], acc[s][u]);
  }

  float p[8][2];
#pragma unroll
  for (int s = 0; s < 8; ++s) { p[s][0] = 0.0f; p[s][1] = 0.0f; }
#pragma unroll
  for (int u = 0; u < 8; ++u) {
    float b1v = b1[oc0 + u];
    float w2a = W2[oc0 + u];
    float w2b = W2[128 + oc0 + u];
#pragma unroll
    for (int s = 0; s < 8; ++s) {
      float o = fmaxf(acc[s][u] + b1v, 0.0f);
      p[s][0] = fmaf(o, w2a, p[s][0]);
      p[s][1] = fmaf(o, w2b, p[s][1]);
    }
  }
#pragma unroll
  for (int off = 1; off < 16; off <<= 1) {
#pragma unroll
    for (int s = 0; s < 8; ++s) {
      p[s][0] += __shfl_xor(p[s][0], off);
      p[s][1] += __shfl_xor(p[s][1], off);
    }
  }
  if (tc == 0) {
    float b20 = b2[0], b21 = b2[1];
#pragma unroll
    for (int s = 0; s < 8; ++s) {
      long row = row0 + r0 + s;
      if (row < nrows) {
        out[row * 2 + 0] = p[s][0] + b20;
        out[row * 2 + 1] = p[s][1] + b21;
      }
    }
  }
}

extern "C" void kernel_launch(void* const* d_in, const int* in_sizes, int n_in,
                              void* d_out, int out_size, void* d_ws, size_t ws_size,
                              hipStream_t stream) {
  const float* time_uniq  = (const float*)d_in[0];
  const int*   time_ptr   = (const int*)d_in[1];
  const float* X          = (const float*)d_in[2];
  const int*   sample_ids = (const int*)d_in[3];
  const float* covs       = (const float*)d_in[4];
  const float* cov_W1     = (const float*)d_in[6];
  const float* cov_b1     = (const float*)d_in[7];
  const float* cov_W2     = (const float*)d_in[8];
  const float* cov_b2     = (const float*)d_in[9];
  const float* gb_Wih     = (const float*)d_in[10];
  const float* gb_Whh     = (const float*)d_in[11];
  const float* gb_bih     = (const float*)d_in[12];
  const float* gb_bhh     = (const float*)d_in[13];
  const float* gx_b       = (const float*)d_in[15];
  const float* ghr_W      = (const float*)d_in[16];
  const float* ghz_W      = (const float*)d_in[17];
  const float* ghh_W      = (const float*)d_in[18];
  const float* out_W1     = (const float*)d_in[19];
  const float* out_b1     = (const float*)d_in[20];
  const float* out_W2     = (const float*)d_in[21];
  const float* out_b2     = (const float*)d_in[22];

  int NE   = in_sizes[0];
  int TOT  = in_sizes[3];
  int IN   = in_sizes[2] / TOT;
  int CH   = in_sizes[7];
  int COV  = in_sizes[6] / CH;
  int B    = in_sizes[4] / COV;
  int OUTD = in_sizes[22];
  int n_steps = out_size / (B * OUTD) - 1;
  int OPE  = TOT / NE;

  char* ws = (char*)d_ws;
  int* evtab = (int*)ws;
  size_t evbytes = (size_t)NE * (size_t)B * sizeof(int);
  size_t off1 = (evbytes + 255) & ~(size_t)255;
  f16* frags = (f16*)(ws + off1);
  size_t off2 = off1 + ((60 * 512 * sizeof(f16) + 255) & ~(size_t)255);
  float* hpath = (float*)(ws + off2);

  hipMemsetAsync(evtab, 0, evbytes, stream);
  build_evtab_kernel<<<NE, 256, 0, stream>>>(sample_ids, time_ptr, evtab, B, OPE);
  pack_frags_kernel<<<60, 64, 0, stream>>>(ghr_W, ghz_W, ghh_W, gb_Whh, gb_Wih,
                                           frags, IN);
  evolve_kernel<<<(B + 15) / 16, 256, 0, stream>>>(
      time_uniq, X, covs, cov_W1, cov_b1, cov_W2, cov_b2,
      gb_bih, gb_bhh, gx_b, frags, evtab, hpath,
      B, NE, n_steps, IN, COV);
  long nrows = (long)(n_steps + 1) * B;
  int hb = (int)((nrows + 127) / 128);
  head_kernel<<<hb, 256, 0, stream>>>(hpath, out_W1, out_b1, out_W2, out_b2,
                                      (float*)d_out, nrows);
}